// Round 4
// baseline (16727.583 us; speedup 1.0000x reference)
//
#include <hip/hip_runtime.h>

#define Tq     2048
#define INq    4
#define UNITSq 256
#define BBq    128
#define NCq    10
#define HBS    288   // hb row stride elems (576B; 576 mod 128 = 64 -> 16-bank parity shift)
#define BBS    160   // bbuf row stride elems (320B; 320 mod 128 = 64)

typedef __bf16 bf16x8 __attribute__((ext_vector_type(8)));
typedef float  f32x4  __attribute__((ext_vector_type(4)));
typedef float  f32x2  __attribute__((ext_vector_type(2)));

__device__ __forceinline__ float rcpf(float x) { return __builtin_amdgcn_rcpf(x); }
__device__ __forceinline__ float tanh_f(float x) {
    float e = __expf(x + x);
    return 1.0f - 2.0f * rcpf(e + 1.0f);
}
__device__ __forceinline__ float lecun_f(float x) {
    float e = __expf(1.332f * x);
    return 1.7159f - 3.4318f * rcpf(e + 1.0f);
}
__device__ __forceinline__ float sigm_f(float x) {
    return rcpf(1.0f + __expf(-x));
}
// select element i (runtime 0..3) from f32x4 via cndmask tree
__device__ __forceinline__ float sel4(f32x4 v, int i) {
    float lo = (i & 1) ? v[1] : v[0];
    float hi = (i & 1) ? v[3] : v[2];
    return (i & 2) ? hi : lo;
}

// 512 blocks x 512 threads (8 waves) -> 2 independent blocks (chains) per CU,
// 4 waves/SIMD: block barrier stalls of one chain hide under the other chain.
// Block owns batch rows [2b, 2b+2). Row replication j&1: A-tile row j holds
// real row (j&1); lane group g's sel4 reg g = tile row 5g = real row g&1.
__global__ __launch_bounds__(512, 4) void cfc_kernel(
    const float* __restrict__ x,
    const float* __restrict__ W_bb, const float* __restrict__ b_bb,
    const float* __restrict__ W_ff1, const float* __restrict__ b_ff1,
    const float* __restrict__ W_ff2, const float* __restrict__ b_ff2,
    const float* __restrict__ W_ta, const float* __restrict__ b_ta,
    const float* __restrict__ W_tb, const float* __restrict__ b_tb,
    const float* __restrict__ W_fc, const float* __restrict__ b_fc,
    float* __restrict__ out)
{
    const int tid = threadIdx.x;
    const int w   = tid >> 6;
    const int l   = tid & 63;
    const int l4  = l >> 4;      // k-group / row-copy select
    const int lc  = l & 15;
    const int bbase = blockIdx.x * 2;

    __shared__ __bf16 hb[4 * HBS];       // rows 0,1 real; 2,3 copies. cols 256..259 = x
    __shared__ __bf16 bbuf[4 * BBS];     // rows 0,1 real; 2,3 copies
    __shared__ float  xstage[2][256];    // 32 steps x 2 rows x 4
    __shared__ float  hsum_lds[2][256];

    // ---------------- weight preload (register-resident B-fragments) ---------
    // P1 heads: tile tl col lc -> unit u = 32w + 2*lc + tl
    bf16x8 WH[3][2][4];
    #pragma unroll
    for (int tl = 0; tl < 2; ++tl) {
        const int u = w * 32 + 2 * lc + tl;
        #pragma unroll
        for (int kt = 0; kt < 4; ++kt) {
            bf16x8 f1, f2, ts;
            #pragma unroll
            for (int j = 0; j < 8; ++j) {
                const int k = kt * 32 + l4 * 8 + j;
                f1[j] = (__bf16)W_ff1[k * UNITSq + u];
                f2[j] = (__bf16)W_ff2[k * UNITSq + u];
                ts[j] = (__bf16)(W_ta[k * UNITSq + u] + W_tb[k * UNITSq + u]);
            }
            WH[0][tl][kt] = f1; WH[1][tl][kt] = f2; WH[2][tl][kt] = ts;
        }
    }
    // P0 backbone: col cb = 16w + lc; kt 0..7 = h rows 4..259, kt 8 = x rows 0..3
    const int cb = w * 16 + lc;
    bf16x8 WB[9];
    #pragma unroll
    for (int kt = 0; kt < 8; ++kt) {
        bf16x8 f;
        #pragma unroll
        for (int j = 0; j < 8; ++j) {
            const int k = kt * 32 + l4 * 8 + j;
            f[j] = (__bf16)W_bb[(4 + k) * BBq + cb];
        }
        WB[kt] = f;
    }
    {
        bf16x8 f;
        #pragma unroll
        for (int j = 0; j < 8; ++j) {
            const int k = l4 * 8 + j;
            f[j] = (k < 4) ? (__bf16)W_bb[k * BBq + cb] : (__bf16)0.0f;
        }
        WB[8] = f;
    }
    const float bias_bb_r = b_bb[cb];
    const int ru0 = w * 32 + 2 * lc;
    const float bf1a = b_ff1[ru0], bf1b = b_ff1[ru0 + 1];
    const float bf2a = b_ff2[ru0], bf2b = b_ff2[ru0 + 1];
    const float bta_ = b_ta[ru0] + b_tb[ru0];
    const float btb_ = b_ta[ru0 + 1] + b_tb[ru0 + 1];

    // ---------------- init ---------------------------------------------------
    for (int i = tid; i < 4 * HBS; i += 512) hb[i] = (__bf16)0.0f;
    if (tid < 256) {    // x chunk 0 staged
        const int r = tid >> 7, off = tid & 127;
        xstage[0][r * 128 + off] = x[((size_t)(bbase + r) * Tq + (off >> 2)) * INq + (off & 3)];
    }
    float xv = 0.f;     // chunk 1 in flight (reg), threads 0..255
    if (tid < 256) {
        const int r = tid >> 7, off = tid & 127;
        xv = x[((size_t)(bbase + r) * Tq + 32 + (off >> 2)) * INq + (off & 3)];
    }
    if (tid < 16) {     // x_0 into hb ext cols (rows 0..3, real row j&1)
        const int r4 = tid >> 2, q = tid & 3;
        hb[r4 * HBS + 256 + q] = (__bf16)x[((size_t)(bbase + (r4 & 1)) * Tq + 0) * INq + q];
    }
    __syncthreads();

    float hsumA = 0.f, hsumB = 0.f;
    const int rowc = lc & 3;             // A-row copy index (real row = rowc&1)

    for (int t = 0; t < Tq; ++t) {
        float xnew = 0.f;
        if (((t & 31) == 0) && tid < 256) {  // prefetch chunk (t>>5)+2 into reg
            const int r = tid >> 7, off = tid & 127;
            int tel = t + 64 + (off >> 2);
            tel = (tel < Tq) ? tel : (Tq - 1);
            xnew = x[((size_t)(bbase + r) * Tq + tel) * INq + (off & 3)];
        }

        // ---- P0: pre = [h|x] @ W_bb (K = 288), 4-way acc split --------------
        f32x4 p0 = {0.f,0.f,0.f,0.f}, p1 = {0.f,0.f,0.f,0.f};
        f32x4 p2 = {0.f,0.f,0.f,0.f}, p3 = {0.f,0.f,0.f,0.f};
        #pragma unroll
        for (int kt = 0; kt < 9; ++kt) {
            bf16x8 a = *(const bf16x8*)&hb[rowc * HBS + kt * 32 + l4 * 8];
            switch (kt & 3) {
                case 0: p0 = __builtin_amdgcn_mfma_f32_16x16x32_bf16(a, WB[kt], p0, 0, 0, 0); break;
                case 1: p1 = __builtin_amdgcn_mfma_f32_16x16x32_bf16(a, WB[kt], p1, 0, 0, 0); break;
                case 2: p2 = __builtin_amdgcn_mfma_f32_16x16x32_bf16(a, WB[kt], p2, 0, 0, 0); break;
                case 3: p3 = __builtin_amdgcn_mfma_f32_16x16x32_bf16(a, WB[kt], p3, 0, 0, 0); break;
            }
        }
        {
            f32x4 s = (p0 + p1) + (p2 + p3);
            float pre = sel4(s, l4) + bias_bb_r;     // real row l4&1, col cb
            bbuf[l4 * BBS + cb] = (__bf16)lecun_f(pre);
        }
        __syncthreads();    // bar A

        // ---- P1: heads (K = 128) --------------------------------------------
        f32x4 acc[3][2] = {};
        #pragma unroll
        for (int kt = 0; kt < 4; ++kt) {
            bf16x8 a = *(const bf16x8*)&bbuf[rowc * BBS + kt * 32 + l4 * 8];
            #pragma unroll
            for (int hh = 0; hh < 3; ++hh)
                #pragma unroll
                for (int tl = 0; tl < 2; ++tl)
                    acc[hh][tl] = __builtin_amdgcn_mfma_f32_16x16x32_bf16(a, WH[hh][tl][kt], acc[hh][tl], 0, 0, 0);
        }
        {   // lane: row-copy l4 (real row l4&1), units ru0, ru0+1
            float f1a = tanh_f(sel4(acc[0][0], l4) + bf1a);
            float f1b = tanh_f(sel4(acc[0][1], l4) + bf1b);
            float f2a = tanh_f(sel4(acc[1][0], l4) + bf2a);
            float f2b = tanh_f(sel4(acc[1][1], l4) + bf2b);
            float tta = sigm_f(sel4(acc[2][0], l4) + bta_);
            float ttb = sigm_f(sel4(acc[2][1], l4) + btb_);
            float ha  = f1a + tta * (f2a - f1a);
            float hbv = f1b + ttb * (f2b - f1b);
            hsumA += ha; hsumB += hbv;
            union { __bf16 b[2]; unsigned int u; } pk;
            pk.b[0] = (__bf16)ha; pk.b[1] = (__bf16)hbv;
            *(unsigned int*)&hb[l4 * HBS + ru0] = pk.u;
        }
        if (w == 7 && l < 16 && t + 1 < Tq) {   // x_{t+1} into hb ext (4 row-copies)
            const int r4 = l >> 2, q = l & 3;
            const int tn = t + 1;
            hb[r4 * HBS + 256 + q] =
                (__bf16)xstage[(tn >> 5) & 1][(r4 & 1) * 128 + (tn & 31) * 4 + q];
        }
        if (((t & 31) == 0) && tid < 256) {     // stage chunk (t>>5)+1 into LDS
            const int r = tid >> 7, off = tid & 127;
            xstage[((t >> 5) + 1) & 1][r * 128 + off] = xv;
            xv = xnew;
        }
        __syncthreads();    // bar B
    }

    // ---------------- epilogue: out = (hsum/T) @ W_fc + b_fc -----------------
    if (l4 < 2)     // groups 0,1 hold real rows 0,1
        *(f32x2*)&hsum_lds[l4][ru0] = (f32x2){hsumA, hsumB};
    __syncthreads();
    if (w == 0 && l < 20) {
        const int r = l / 10, c = l % 10;
        float s = 0.f;
        #pragma unroll 8
        for (int u = 0; u < 256; ++u)
            s += hsum_lds[r][u] * W_fc[u * NCq + c];
        out[(bbase + r) * NCq + c] = s * (1.0f / Tq) + b_fc[c];
    }
}

extern "C" void kernel_launch(void* const* d_in, const int* in_sizes, int n_in,
                              void* d_out, int out_size, void* d_ws, size_t ws_size,
                              hipStream_t stream) {
    const float* x     = (const float*)d_in[0];
    const float* W_bb  = (const float*)d_in[1];
    const float* b_bb  = (const float*)d_in[2];
    const float* W_ff1 = (const float*)d_in[3];
    const float* b_ff1 = (const float*)d_in[4];
    const float* W_ff2 = (const float*)d_in[5];
    const float* b_ff2 = (const float*)d_in[6];
    const float* W_ta  = (const float*)d_in[7];
    const float* b_ta  = (const float*)d_in[8];
    const float* W_tb  = (const float*)d_in[9];
    const float* b_tb  = (const float*)d_in[10];
    const float* W_fc  = (const float*)d_in[11];
    const float* b_fc  = (const float*)d_in[12];
    float* out = (float*)d_out;

    hipLaunchKernelGGL(cfc_kernel, dim3(512), dim3(512), 0, stream,
                       x, W_bb, b_bb, W_ff1, b_ff1, W_ff2, b_ff2,
                       W_ta, b_ta, W_tb, b_tb, W_fc, b_fc, out);
}

// Round 5
// 3569.246 us; speedup vs baseline: 4.6866x; 4.6866x over previous
//
#include <hip/hip_runtime.h>

#define Tq     2048
#define INq    4
#define UNITSq 256
#define BBq    128
#define NCq    10
#define HBS    288   // hb row stride elems (576B; 576 mod 128B = 64 -> 16-bank parity shift)
#define BBS    160   // bbuf row stride elems (320B; 320 mod 128B = 64)

typedef __bf16 bf16x8 __attribute__((ext_vector_type(8)));
typedef float  f32x4  __attribute__((ext_vector_type(4)));
typedef float  f32x2  __attribute__((ext_vector_type(2)));

__device__ __forceinline__ float rcpf(float x) { return __builtin_amdgcn_rcpf(x); }
__device__ __forceinline__ float tanh_f(float x) {
    float e = __expf(x + x);
    return 1.0f - 2.0f * rcpf(e + 1.0f);
}
__device__ __forceinline__ float lecun_f(float x) {
    float e = __expf(1.332f * x);
    return 1.7159f - 3.4318f * rcpf(e + 1.0f);
}
__device__ __forceinline__ float sigm_f(float x) {
    return rcpf(1.0f + __expf(-x));
}
__device__ __forceinline__ float sel4(f32x4 v, int i) {
    float lo = (i & 1) ? v[1] : v[0];
    float hi = (i & 1) ? v[3] : v[2];
    return (i & 2) ? hi : lo;
}

// 256 blocks x 512 threads. Block owns batch rows [4b,4b+4) as TWO 2-row
// chains (A: rows 0,1; B: rows 2,3), phase-shifted by half a step:
//   X(t): P1_A(t) || P0_B(t)   -> bar
//   Y(t): P0_A(t+1) || P1_B(t) -> bar
// Weights register-resident ONCE, shared by both chains. Each interval has
// two independent MFMA dep-graphs -> latency hiding via ILP, not occupancy.
// Row replication j&1: A-tile row j holds real row (j&1).
__global__ __launch_bounds__(512, 2) void cfc_kernel(
    const float* __restrict__ x,
    const float* __restrict__ W_bb, const float* __restrict__ b_bb,
    const float* __restrict__ W_ff1, const float* __restrict__ b_ff1,
    const float* __restrict__ W_ff2, const float* __restrict__ b_ff2,
    const float* __restrict__ W_ta, const float* __restrict__ b_ta,
    const float* __restrict__ W_tb, const float* __restrict__ b_tb,
    const float* __restrict__ W_fc, const float* __restrict__ b_fc,
    float* __restrict__ out)
{
    const int tid = threadIdx.x;
    const int w   = tid >> 6;
    const int l   = tid & 63;
    const int l4  = l >> 4;
    const int lc  = l & 15;
    const int bbase = blockIdx.x * 4;

    __shared__ __bf16 hbA[4 * HBS], hbB[4 * HBS];   // cols 0..255 h, 256..259 x, rest 0
    __shared__ __bf16 bbA[4 * BBS], bbB[4 * BBS];
    __shared__ float  xstage[2][512];               // 32 steps x 4 block-rows x 4
    __shared__ float  hsum_lds[4][256];

    // ---------------- weight preload (register-resident, shared) -------------
    bf16x8 WH[3][2][4];
    #pragma unroll
    for (int tl = 0; tl < 2; ++tl) {
        const int u = w * 32 + 2 * lc + tl;
        #pragma unroll
        for (int kt = 0; kt < 4; ++kt) {
            bf16x8 f1, f2, ts;
            #pragma unroll
            for (int j = 0; j < 8; ++j) {
                const int k = kt * 32 + l4 * 8 + j;
                f1[j] = (__bf16)W_ff1[k * UNITSq + u];
                f2[j] = (__bf16)W_ff2[k * UNITSq + u];
                ts[j] = (__bf16)(W_ta[k * UNITSq + u] + W_tb[k * UNITSq + u]);
            }
            WH[0][tl][kt] = f1; WH[1][tl][kt] = f2; WH[2][tl][kt] = ts;
        }
    }
    const int cb = w * 16 + lc;
    bf16x8 WB[9];
    #pragma unroll
    for (int kt = 0; kt < 8; ++kt) {
        bf16x8 f;
        #pragma unroll
        for (int j = 0; j < 8; ++j) {
            const int k = kt * 32 + l4 * 8 + j;
            f[j] = (__bf16)W_bb[(4 + k) * BBq + cb];
        }
        WB[kt] = f;
    }
    {
        bf16x8 f;
        #pragma unroll
        for (int j = 0; j < 8; ++j) {
            const int k = l4 * 8 + j;
            f[j] = (k < 4) ? (__bf16)W_bb[k * BBq + cb] : (__bf16)0.0f;
        }
        WB[8] = f;
    }
    const float bias_bb_r = b_bb[cb];
    const int ru0 = w * 32 + 2 * lc;
    const float bf1a = b_ff1[ru0], bf1b = b_ff1[ru0 + 1];
    const float bf2a = b_ff2[ru0], bf2b = b_ff2[ru0 + 1];
    const float bta_ = b_ta[ru0] + b_tb[ru0];
    const float btb_ = b_ta[ru0 + 1] + b_tb[ru0 + 1];

    // ---------------- init ---------------------------------------------------
    for (int i = tid; i < 4 * HBS; i += 512) { hbA[i] = (__bf16)0.0f; hbB[i] = (__bf16)0.0f; }
    {
        const int r = tid >> 7, off = tid & 127;
        xstage[0][r * 128 + off] = x[((size_t)(bbase + r) * Tq + (off >> 2)) * INq + (off & 3)];
    }
    float xv;
    {
        const int r = tid >> 7, off = tid & 127;
        xv = x[((size_t)(bbase + r) * Tq + 32 + (off >> 2)) * INq + (off & 3)];
    }
    if (tid < 32) {     // x_0 into ext cols of both chains (4 row-copies each)
        const int cB = tid >> 4;                   // 0 = chain A, 1 = chain B
        const int r4 = (tid & 15) >> 2, q = tid & 3;
        const float v = x[((size_t)(bbase + cB * 2 + (r4 & 1)) * Tq + 0) * INq + q];
        (cB ? hbB : hbA)[r4 * HBS + 256 + q] = (__bf16)v;
    }
    __syncthreads();

    float hsA0 = 0.f, hsA1 = 0.f, hsB0 = 0.f, hsB1 = 0.f;
    const int rowc = lc & 3;

    // ---- phase lambdas (capture weights/ids by ref) --------------------------
    auto P0 = [&](const __bf16* __restrict__ hbc, __bf16* __restrict__ bbc) {
        f32x4 p0 = {0.f,0.f,0.f,0.f}, p1 = {0.f,0.f,0.f,0.f};
        f32x4 p2 = {0.f,0.f,0.f,0.f}, p3 = {0.f,0.f,0.f,0.f};
        #pragma unroll
        for (int kt = 0; kt < 9; ++kt) {
            bf16x8 a = *(const bf16x8*)&hbc[rowc * HBS + kt * 32 + l4 * 8];
            switch (kt & 3) {
                case 0: p0 = __builtin_amdgcn_mfma_f32_16x16x32_bf16(a, WB[kt], p0, 0, 0, 0); break;
                case 1: p1 = __builtin_amdgcn_mfma_f32_16x16x32_bf16(a, WB[kt], p1, 0, 0, 0); break;
                case 2: p2 = __builtin_amdgcn_mfma_f32_16x16x32_bf16(a, WB[kt], p2, 0, 0, 0); break;
                case 3: p3 = __builtin_amdgcn_mfma_f32_16x16x32_bf16(a, WB[kt], p3, 0, 0, 0); break;
            }
        }
        f32x4 s = (p0 + p1) + (p2 + p3);
        float pre = sel4(s, l4) + bias_bb_r;
        bbc[l4 * BBS + cb] = (__bf16)lecun_f(pre);
    };
    auto P1 = [&](const __bf16* __restrict__ bbc, __bf16* __restrict__ hbc,
                  float& s0, float& s1) {
        f32x4 acc[3][2] = {};
        #pragma unroll
        for (int kt = 0; kt < 4; ++kt) {
            bf16x8 a = *(const bf16x8*)&bbc[rowc * BBS + kt * 32 + l4 * 8];
            #pragma unroll
            for (int hh = 0; hh < 3; ++hh)
                #pragma unroll
                for (int tl = 0; tl < 2; ++tl)
                    acc[hh][tl] = __builtin_amdgcn_mfma_f32_16x16x32_bf16(a, WH[hh][tl][kt], acc[hh][tl], 0, 0, 0);
        }
        float f1a = tanh_f(sel4(acc[0][0], l4) + bf1a);
        float f1b = tanh_f(sel4(acc[0][1], l4) + bf1b);
        float f2a = tanh_f(sel4(acc[1][0], l4) + bf2a);
        float f2b = tanh_f(sel4(acc[1][1], l4) + bf2b);
        float tta = sigm_f(sel4(acc[2][0], l4) + bta_);
        float ttb = sigm_f(sel4(acc[2][1], l4) + btb_);
        float ha  = f1a + tta * (f2a - f1a);
        float hbv = f1b + ttb * (f2b - f1b);
        s0 += ha; s1 += hbv;
        union { __bf16 b[2]; unsigned int u; } pk;
        pk.b[0] = (__bf16)ha; pk.b[1] = (__bf16)hbv;
        *(unsigned int*)&hbc[l4 * HBS + ru0] = pk.u;
    };

    // ---- prologue: P0_A(0) ---------------------------------------------------
    P0(hbA, bbA);
    __syncthreads();

    // ---- main loop: t = 0 .. Tq-2 (hot body branch-free except tiny guards) --
    for (int t = 0; t < Tq - 1; ++t) {
        float xnew = 0.f;
        if ((t & 31) == 0) {                       // prefetch chunk (t>>5)+2
            const int r = tid >> 7, off = tid & 127;
            int tel = t + 64 + (off >> 2);
            tel = (tel < Tq) ? tel : (Tq - 1);
            xnew = x[((size_t)(bbase + r) * Tq + tel) * INq + (off & 3)];
        }
        // X(t): P1_A(t) || P0_B(t)
        P1(bbA, hbA, hsA0, hsA1);
        P0(hbB, bbB);
        if (w == 7 && l < 16) {                    // x_{t+1} -> hbA ext
            const int r4 = l >> 2, q = l & 3, tn = t + 1;
            hbA[r4 * HBS + 256 + q] =
                (__bf16)xstage[(tn >> 5) & 1][(r4 & 1) * 128 + (tn & 31) * 4 + q];
        }
        __syncthreads();
        // Y(t): P0_A(t+1) || P1_B(t)
        P0(hbA, bbA);
        P1(bbB, hbB, hsB0, hsB1);
        if (w == 6 && l < 16) {                    // x_{t+1} -> hbB ext
            const int r4 = l >> 2, q = l & 3, tn = t + 1;
            hbB[r4 * HBS + 256 + q] =
                (__bf16)xstage[(tn >> 5) & 1][(2 + (r4 & 1)) * 128 + (tn & 31) * 4 + q];
        }
        if ((t & 31) == 0) {                       // stage chunk (t>>5)+1
            const int r = tid >> 7, off = tid & 127;
            xstage[((t >> 5) + 1) & 1][r * 128 + off] = xv;
            xv = xnew;
        }
        __syncthreads();
    }
    // ---- tail: t = Tq-1 ------------------------------------------------------
    P1(bbA, hbA, hsA0, hsA1);
    P0(hbB, bbB);
    __syncthreads();
    P1(bbB, hbB, hsB0, hsB1);

    // ---- epilogue: out = (hsum/T) @ W_fc + b_fc ------------------------------
    if (l4 < 2) {   // groups 0,1 hold real rows 0,1 of each chain
        *(f32x2*)&hsum_lds[l4][ru0]     = (f32x2){hsA0, hsA1};
        *(f32x2*)&hsum_lds[2 + l4][ru0] = (f32x2){hsB0, hsB1};
    }
    __syncthreads();
    if (w == 0 && l < 40) {
        const int r = l / 10, c = l % 10;
        float s = 0.f;
        #pragma unroll 8
        for (int u = 0; u < 256; ++u)
            s += hsum_lds[r][u] * W_fc[u * NCq + c];
        out[(bbase + r) * NCq + c] = s * (1.0f / Tq) + b_fc[c];
    }
}

extern "C" void kernel_launch(void* const* d_in, const int* in_sizes, int n_in,
                              void* d_out, int out_size, void* d_ws, size_t ws_size,
                              hipStream_t stream) {
    const float* x     = (const float*)d_in[0];
    const float* W_bb  = (const float*)d_in[1];
    const float* b_bb  = (const float*)d_in[2];
    const float* W_ff1 = (const float*)d_in[3];
    const float* b_ff1 = (const float*)d_in[4];
    const float* W_ff2 = (const float*)d_in[5];
    const float* b_ff2 = (const float*)d_in[6];
    const float* W_ta  = (const float*)d_in[7];
    const float* b_ta  = (const float*)d_in[8];
    const float* W_tb  = (const float*)d_in[9];
    const float* b_tb  = (const float*)d_in[10];
    const float* W_fc  = (const float*)d_in[11];
    const float* b_fc  = (const float*)d_in[12];
    float* out = (float*)d_out;

    hipLaunchKernelGGL(cfc_kernel, dim3(256), dim3(512), 0, stream,
                       x, W_bb, b_bb, W_ff1, b_ff1, W_ff2, b_ff2,
                       W_ta, b_ta, W_tb, b_tb, W_fc, b_fc, out);
}

// Round 6
// 1825.299 us; speedup vs baseline: 9.1643x; 1.9554x over previous
//
#include <hip/hip_runtime.h>

#define Tq     2048
#define INq    4
#define UNITSq 256
#define BBq    128
#define NCq    10
#define HBS    288   // hb row stride elems (576B; 576 mod 128B = 64 -> rows alternate 16-bank halves)
#define BBS    160   // bbuf row stride elems (320B; same parity trick)

typedef __bf16 bf16x8 __attribute__((ext_vector_type(8)));
typedef float  f32x4  __attribute__((ext_vector_type(4)));
typedef float  f32x2  __attribute__((ext_vector_type(2)));

__device__ __forceinline__ float rcpf(float x) { return __builtin_amdgcn_rcpf(x); }
__device__ __forceinline__ float tanh_f(float x) {
    float e = __expf(x + x);
    return 1.0f - 2.0f * rcpf(e + 1.0f);
}
__device__ __forceinline__ float lecun_f(float x) {
    float e = __expf(1.332f * x);
    return 1.7159f - 3.4318f * rcpf(e + 1.0f);
}
__device__ __forceinline__ float sigm_f(float x) {
    return rcpf(1.0f + __expf(-x));
}
__device__ __forceinline__ float sel4(f32x4 v, int i) {
    float lo = (i & 1) ? v[1] : v[0];
    float hi = (i & 1) ? v[3] : v[2];
    return (i & 2) ? hi : lo;
}

// LDS-only barrier: drain ds ops, block barrier, fence scheduler both sides
// (rule 18: sched_barrier(0) so MFMA/VALU aren't hoisted across).
__device__ __forceinline__ void bar_lds() {
    __builtin_amdgcn_sched_barrier(0);
    asm volatile("s_waitcnt lgkmcnt(0)" ::: "memory");
    __builtin_amdgcn_s_barrier();
    __builtin_amdgcn_sched_barrier(0);
}

// 256 blocks x 512 threads (R3 structure). Block owns batch rows [4b,4b+4).
// Row replication j&3: A-tile row j = real row (j&3); C/D reg i = real row i
// in every lane -> post-MFMA redistribution is a register select (sel4).
// Wave w: P0 cols [16w,16w+16); P1 units u = 32w + 2*lc + {0,1}.
__global__ __launch_bounds__(512, 2) void cfc_kernel(
    const float* __restrict__ x,
    const float* __restrict__ W_bb, const float* __restrict__ b_bb,
    const float* __restrict__ W_ff1, const float* __restrict__ b_ff1,
    const float* __restrict__ W_ff2, const float* __restrict__ b_ff2,
    const float* __restrict__ W_ta, const float* __restrict__ b_ta,
    const float* __restrict__ W_tb, const float* __restrict__ b_tb,
    const float* __restrict__ W_fc, const float* __restrict__ b_fc,
    float* __restrict__ out)
{
    const int tid = threadIdx.x;
    const int w   = tid >> 6;
    const int l   = tid & 63;
    const int l4  = l >> 4;
    const int lc  = l & 15;
    const int bbase = blockIdx.x * 4;

    __shared__ __bf16 hb[4 * HBS];       // cols 0..255 h, 256..259 x, rest 0
    __shared__ __bf16 bbuf[4 * BBS];
    __shared__ float  xstage[2][512];    // 32 steps x 4 rows x 4
    __shared__ float  hsum_lds[4][256];

    // ---------------- weight preload (register-resident B-fragments) ---------
    bf16x8 WH[3][2][4];                  // [ff1, ff2, ta+tb][unit tile][ktile]
    #pragma unroll
    for (int tl = 0; tl < 2; ++tl) {
        const int u = w * 32 + 2 * lc + tl;
        #pragma unroll
        for (int kt = 0; kt < 4; ++kt) {
            bf16x8 f1, f2, ts;
            #pragma unroll
            for (int j = 0; j < 8; ++j) {
                const int k = kt * 32 + l4 * 8 + j;
                f1[j] = (__bf16)W_ff1[k * UNITSq + u];
                f2[j] = (__bf16)W_ff2[k * UNITSq + u];
                ts[j] = (__bf16)(W_ta[k * UNITSq + u] + W_tb[k * UNITSq + u]);
            }
            WH[0][tl][kt] = f1; WH[1][tl][kt] = f2; WH[2][tl][kt] = ts;
        }
    }
    const int cb = w * 16 + lc;
    bf16x8 WB[9];
    #pragma unroll
    for (int kt = 0; kt < 8; ++kt) {
        bf16x8 f;
        #pragma unroll
        for (int j = 0; j < 8; ++j) {
            const int k = kt * 32 + l4 * 8 + j;
            f[j] = (__bf16)W_bb[(4 + k) * BBq + cb];
        }
        WB[kt] = f;
    }
    {
        bf16x8 f;
        #pragma unroll
        for (int j = 0; j < 8; ++j) {
            const int k = l4 * 8 + j;
            f[j] = (k < 4) ? (__bf16)W_bb[k * BBq + cb] : (__bf16)0.0f;
        }
        WB[8] = f;
    }
    const float bias_bb_r = b_bb[cb];
    const int ru0 = w * 32 + 2 * lc;
    const float bf1a = b_ff1[ru0], bf1b = b_ff1[ru0 + 1];
    const float bf2a = b_ff2[ru0], bf2b = b_ff2[ru0 + 1];
    const float bta_ = b_ta[ru0] + b_tb[ru0];
    const float btb_ = b_ta[ru0 + 1] + b_tb[ru0 + 1];

    // ---------------- init ---------------------------------------------------
    for (int i = tid; i < 4 * HBS; i += 512) hb[i] = (__bf16)0.0f;
    {
        const int r = tid >> 7, off = tid & 127;
        xstage[0][r * 128 + off] = x[((size_t)(bbase + r) * Tq + (off >> 2)) * INq + (off & 3)];
    }
    float xv;   // holds chunk c+1 while chunk c is staged in LDS
    {
        const int r = tid >> 7, off = tid & 127;
        xv = x[((size_t)(bbase + r) * Tq + 32 + (off >> 2)) * INq + (off & 3)];
    }
    if (tid < 16) {
        const int r = tid >> 2, q = tid & 3;
        hb[r * HBS + 256 + q] = (__bf16)x[((size_t)(bbase + r) * Tq + 0) * INq + q];
    }
    __syncthreads();

    float hsumA = 0.f, hsumB = 0.f;
    const int rowc = lc & 3;             // replicated A-row

    for (int c = 0; c < 64; ++c) {
        // ---- chunk head: stage chunk c+1 (from xv) into buf[(c+1)&1];
        //      prefetch chunk c+2 into xv.  Parity-disjoint from all reads
        //      in this chunk (reads use buf[c&1] except last step's buf[(c+1)&1],
        //      which is written here, well before it).
        {
            const int r = tid >> 7, off = tid & 127;
            xstage[(c + 1) & 1][r * 128 + off] = xv;
            int tel = c * 32 + 64 + (off >> 2);
            tel = (tel < Tq) ? tel : (Tq - 1);
            xv = x[((size_t)(bbase + r) * Tq + tel) * INq + (off & 3)];
        }

        for (int i = 0; i < 32; ++i) {
            const int t = c * 32 + i;

            // ---- P0: pre = [h|x] @ W_bb (K = 288), 2-acc split --------------
            f32x4 p0 = {0.f,0.f,0.f,0.f}, p1 = {0.f,0.f,0.f,0.f};
            __builtin_amdgcn_s_setprio(1);
            #pragma unroll
            for (int kt = 0; kt < 9; ++kt) {
                bf16x8 a = *(const bf16x8*)&hb[rowc * HBS + kt * 32 + l4 * 8];
                if (kt & 1) p1 = __builtin_amdgcn_mfma_f32_16x16x32_bf16(a, WB[kt], p1, 0, 0, 0);
                else        p0 = __builtin_amdgcn_mfma_f32_16x16x32_bf16(a, WB[kt], p0, 0, 0, 0);
            }
            __builtin_amdgcn_s_setprio(0);
            {
                f32x4 s = p0 + p1;
                float pre = sel4(s, l4) + bias_bb_r;     // real row l4, col cb
                bbuf[l4 * BBS + cb] = (__bf16)lecun_f(pre);
            }
            bar_lds();   // bar A

            // ---- P1: heads (K = 128) ----------------------------------------
            f32x4 acc[3][2] = {};
            __builtin_amdgcn_s_setprio(1);
            #pragma unroll
            for (int kt = 0; kt < 4; ++kt) {
                bf16x8 a = *(const bf16x8*)&bbuf[rowc * BBS + kt * 32 + l4 * 8];
                #pragma unroll
                for (int hh = 0; hh < 3; ++hh)
                    #pragma unroll
                    for (int tl = 0; tl < 2; ++tl)
                        acc[hh][tl] = __builtin_amdgcn_mfma_f32_16x16x32_bf16(a, WH[hh][tl][kt], acc[hh][tl], 0, 0, 0);
            }
            __builtin_amdgcn_s_setprio(0);
            {   // lane: row l4, units ru0, ru0+1 (register selects, no LDS)
                float f1a = tanh_f(sel4(acc[0][0], l4) + bf1a);
                float f1b = tanh_f(sel4(acc[0][1], l4) + bf1b);
                float f2a = tanh_f(sel4(acc[1][0], l4) + bf2a);
                float f2b = tanh_f(sel4(acc[1][1], l4) + bf2b);
                float tta = sigm_f(sel4(acc[2][0], l4) + bta_);
                float ttb = sigm_f(sel4(acc[2][1], l4) + btb_);
                float ha  = f1a + tta * (f2a - f1a);
                float hbv = f1b + ttb * (f2b - f1b);
                hsumA += ha; hsumB += hbv;
                union { __bf16 b[2]; unsigned int u; } pk;
                pk.b[0] = (__bf16)ha; pk.b[1] = (__bf16)hbv;
                *(unsigned int*)&hb[l4 * HBS + ru0] = pk.u;
            }
            if (w == 7 && l < 16 && t + 1 < Tq) {   // x_{t+1} into hb ext cols
                const int r = l >> 2, q = l & 3;
                const int tn = t + 1;
                hb[r * HBS + 256 + q] =
                    (__bf16)xstage[(tn >> 5) & 1][r * 128 + (tn & 31) * 4 + q];
            }
            bar_lds();   // bar B
        }
    }

    // ---------------- epilogue: out = (hsum/T) @ W_fc + b_fc -----------------
    *(f32x2*)&hsum_lds[l4][ru0] = (f32x2){hsumA, hsumB};
    __syncthreads();
    if (w == 0 && l < 40) {
        const int r = l / 10, c = l % 10;
        float s = 0.f;
        #pragma unroll 8
        for (int u = 0; u < 256; ++u)
            s += hsum_lds[r][u] * W_fc[u * NCq + c];
        out[(bbase + r) * NCq + c] = s * (1.0f / Tq) + b_fc[c];
    }
}

extern "C" void kernel_launch(void* const* d_in, const int* in_sizes, int n_in,
                              void* d_out, int out_size, void* d_ws, size_t ws_size,
                              hipStream_t stream) {
    const float* x     = (const float*)d_in[0];
    const float* W_bb  = (const float*)d_in[1];
    const float* b_bb  = (const float*)d_in[2];
    const float* W_ff1 = (const float*)d_in[3];
    const float* b_ff1 = (const float*)d_in[4];
    const float* W_ff2 = (const float*)d_in[5];
    const float* b_ff2 = (const float*)d_in[6];
    const float* W_ta  = (const float*)d_in[7];
    const float* b_ta  = (const float*)d_in[8];
    const float* W_tb  = (const float*)d_in[9];
    const float* b_tb  = (const float*)d_in[10];
    const float* W_fc  = (const float*)d_in[11];
    const float* b_fc  = (const float*)d_in[12];
    float* out = (float*)d_out;

    hipLaunchKernelGGL(cfc_kernel, dim3(256), dim3(512), 0, stream,
                       x, W_bb, b_bb, W_ff1, b_ff1, W_ff2, b_ff2,
                       W_ta, b_ta, W_tb, b_tb, W_fc, b_fc, out);
}